// Round 8
// baseline (783.326 us; speedup 1.0000x reference)
//
#include <hip/hip_runtime.h>

#define NB 16
#define NT 128
#define NC 64
#define NU 128
#define UNFOLDS 6
#define LTC_EPS 1e-8f
#define LOG2E 1.44269504088896340736f
#define LN2   0.69314718055994530942f

typedef float f32x2 __attribute__((ext_vector_type(2)));

__device__ __forceinline__ float fast_softplus(float x) {
    return LN2 * __builtin_amdgcn_logf(1.0f + __builtin_amdgcn_exp2f(x * LOG2E));
}

template<int CTRL>
__device__ __forceinline__ float qperm(float x) {
    return __int_as_float(__builtin_amdgcn_update_dpp(
        0, __float_as_int(x), CTRL, 0xF, 0xF, true));
}
// sum over the 8 lanes of a k-group; all stages DPP (VALU pipe, no LDS)
__device__ __forceinline__ float sum8(float x) {
    x += qperm<0xB1>(x);    // quad_perm xor-1
    x += qperm<0x4E>(x);    // quad_perm xor-2
    x += qperm<0x141>(x);   // row_half_mirror (verified r7)
    return x;
}

// ---------------- Kernel 1: sensory precompute (fully parallel) ----------------
__global__ __launch_bounds__(128)
void ltc_sens_kernel(const float* __restrict__ x,
                     const float* __restrict__ ssigma,
                     const float* __restrict__ smu,
                     const float* __restrict__ sw,
                     const float* __restrict__ serev,
                     const float* __restrict__ iw,
                     const float* __restrict__ ib,
                     float2* __restrict__ sens)
{
    __shared__ float xt[NC];
    const int blk = blockIdx.x;
    const int b = blk >> 7;
    const int t = blk & (NT - 1);
    const int j = threadIdx.x;
    if (j < NC) xt[j] = fmaf(x[(b * NT + t) * NC + j], iw[j], ib[j]);
    __syncthreads();

    float n0 = 0.f, n1 = 0.f, d0 = 0.f, d1 = 0.f;
#pragma unroll 8
    for (int c = 0; c < NC; ++c) {
        const int idx = c * NU + j;
        float sg = ssigma[idx];
        float m  = smu[idx];
        float wp = fast_softplus(sw[idx]);
        float er = serev[idx];
        float tt = (m - xt[c]) * (sg * LOG2E);
        float e  = __builtin_amdgcn_exp2f(tt);
        float r  = __builtin_amdgcn_rcpf(1.0f + e);
        float wr = wp * r;
        if (c & 1) { n1 = fmaf(wr, er, n1); d1 += wr; }
        else       { n0 = fmaf(wr, er, n0); d0 += wr; }
    }
    sens[(b * NT + t) * NU + j] = make_float2(n0 + n1, d0 + d1);
}

// ---------------- Kernel 2: sequential scan, 8 lanes per post-unit ----------------
__global__ __launch_bounds__(1024, 4)
void ltc_seq_kernel(const float* __restrict__ h0,
                    const float* __restrict__ gleak,
                    const float* __restrict__ vleak,
                    const float* __restrict__ cm,
                    const float* __restrict__ sigma,
                    const float* __restrict__ mu,
                    const float* __restrict__ w,
                    const float* __restrict__ erev,
                    const float* __restrict__ ow,
                    const float* __restrict__ ob,
                    const float2* __restrict__ sens,
                    float* __restrict__ out)
{
    __shared__ __align__(16) float v_lds[2][NU];

    const int tid = threadIdx.x;
    const int b   = blockIdx.x;
    const int j   = tid >> 3;   // post-unit (128)
    const int k   = tid & 7;    // pre-chunk (8 x 16 rows)

    // Params matched to b128 reads: chunk m reads pre-rows
    // i = k*16 + ((m+k)&3)*4 + {0..3}; slot 2m+h covers elems 2h,2h+1.
    // Rotation (m+k)&3 -> at each read instr, lanes k/k+4 pair 2-way (free),
    // others hit distinct bank groups.
    f32x2 rA2[8], rB2[8], rW2[8], aW2[8];
#pragma unroll
    for (int m = 0; m < 4; ++m) {
        const int rot = (m + k) & 3;
#pragma unroll
        for (int h = 0; h < 2; ++h) {
            const int c   = 2 * m + h;
            const int i0  = (k << 4) + (rot << 2) + 2 * h;
            const int id0 = i0 * NU + j;
            const int id1 = id0 + NU;
            const float sg0 = sigma[id0], sg1 = sigma[id1];
            const float m0  = mu[id0],    m1  = mu[id1];
            const float wp0 = fast_softplus(w[id0]), wp1 = fast_softplus(w[id1]);
            const float er0 = erev[id0],  er1 = erev[id1];
            f32x2 a;  a.x = -sg0 * LOG2E;  a.y = -sg1 * LOG2E;
            f32x2 bb; bb.x = -a.x * m0;    bb.y = -a.y * m1;
            f32x2 ww; ww.x = wp0 * er0;    ww.y = wp1 * er1;
            f32x2 aw; aw.x = wp0;          aw.y = wp1;     // |w| (er = ±1)
            rA2[c] = a; rB2[c] = bb; rW2[c] = ww; aW2[c] = aw;
        }
    }

    const float cmt    = 6.0f * fast_softplus(cm[j]);
    const float gl     = fast_softplus(gleak[j]);
    const float glv    = gl * vleak[j];
    const float cmt_gl = cmt + gl + LTC_EPS;
    const float owj    = ow[j];
    const float obj    = ob[j];
    float vj = h0[b * NU + j];
    if (k == 0) v_lds[0][j] = vj;
    __syncthreads();

    int p = 0;
    float2 s_cur = sens[b * NT * NU + j];

    for (int t = 0; t < NT; ++t) {
        // register pin (zero instructions; blocks reload/remat schemes)
#pragma unroll
        for (int q = 0; q < 8; ++q) {
            asm volatile("" : "+v"(rA2[q]), "+v"(rB2[q]), "+v"(rW2[q]), "+v"(aW2[q]));
        }

        // Fold the per-step constants into the reduction via lane-uniform
        // 1/8 injections (exact: 8 equal addends, /8 is a power of two).
        const float nb = 0.125f * (s_cur.x + glv);
        const float db = 0.125f * (s_cur.y + cmt_gl);
        const int tn = (t + 1 < NT) ? (t + 1) : t;
        const float2 s_next = sens[(b * NT + tn) * NU + j];   // prefetch

#pragma unroll
        for (int u = 0; u < UNFOLDS; ++u) {
            f32x2 n2 = {nb, 0.f};
            f32x2 d2 = {db, 0.f};
#pragma unroll
            for (int m = 0; m < 4; ++m) {
                const float4 vv = *(const float4*)&v_lds[p][(k << 4) + (((m + k) & 3) << 2)];
                const f32x2 v0 = {vv.x, vv.y};
                const f32x2 v1 = {vv.z, vv.w};
                const f32x2 t0 = rA2[2 * m] * v0 + rB2[2 * m];
                const f32x2 t1 = rA2[2 * m + 1] * v1 + rB2[2 * m + 1];
                f32x2 e0, e1;
                e0.x = __builtin_amdgcn_exp2f(t0.x);
                e0.y = __builtin_amdgcn_exp2f(t0.y);
                e1.x = __builtin_amdgcn_exp2f(t1.x);
                e1.y = __builtin_amdgcn_exp2f(t1.y);
                const f32x2 one = {1.0f, 1.0f};
                const f32x2 u0 = e0 + one;
                const f32x2 u1 = e1 + one;
                // quad-shared reciprocal: |v|<1 (provable) => t<21 => prod<2^84
                const float p01 = u0.x * u0.y;
                const float p23 = u1.x * u1.y;
                const float rall = __builtin_amdgcn_rcpf(p01 * p23);
                const float r01 = rall * p23;     // 1/p01
                const float r23 = rall * p01;     // 1/p23
                const f32x2 rr0 = {r01, r01};
                const f32x2 rr1 = {r23, r23};
                const f32x2 r0 = rr0 * __builtin_shufflevector(u0, u0, 1, 0);
                const f32x2 r1 = rr1 * __builtin_shufflevector(u1, u1, 1, 0);
                n2 = rW2[2 * m] * r0 + n2;
                n2 = rW2[2 * m + 1] * r1 + n2;
                d2 = aW2[2 * m] * r0 + d2;
                d2 = aW2[2 * m + 1] * r1 + d2;
            }
            const float wn = sum8(n2.x + n2.y);   // includes snum+glv
            const float wd = sum8(d2.x + d2.y);   // includes sden+cmt+gl+eps
            const float numf = fmaf(cmt, vj, wn);
            vj = numf * __builtin_amdgcn_rcpf(wd);   // redundant in 8 lanes
            if (k == 0) v_lds[p ^ 1][j] = vj;
            __syncthreads();                         // one barrier per unfold
            p ^= 1;
        }

        if (k == 0) out[(b * NT + t) * NU + j] = fmaf(vj, owj, obj);
        s_cur = s_next;
    }
    if (k == 0) out[NB * NT * NU + b * NU + j] = vj;    // h_final
}

extern "C" void kernel_launch(void* const* d_in, const int* in_sizes, int n_in,
                              void* d_out, int out_size, void* d_ws, size_t ws_size,
                              hipStream_t stream) {
    const float* x      = (const float*)d_in[0];
    const float* h0     = (const float*)d_in[1];
    const float* gleak  = (const float*)d_in[2];
    const float* vleak  = (const float*)d_in[3];
    const float* cm     = (const float*)d_in[4];
    const float* sigma  = (const float*)d_in[5];
    const float* mu     = (const float*)d_in[6];
    const float* w      = (const float*)d_in[7];
    const float* erev   = (const float*)d_in[8];
    const float* ssig   = (const float*)d_in[9];
    const float* smu    = (const float*)d_in[10];
    const float* sw     = (const float*)d_in[11];
    const float* serev  = (const float*)d_in[12];
    const float* iw     = (const float*)d_in[13];
    const float* ibv    = (const float*)d_in[14];
    const float* ow     = (const float*)d_in[15];
    const float* ob     = (const float*)d_in[16];
    float* out = (float*)d_out;

    float2* sens = (float2*)d_ws;   // 2 MB scratch
    ltc_sens_kernel<<<NB * NT, 128, 0, stream>>>(x, ssig, smu, sw, serev, iw, ibv, sens);
    ltc_seq_kernel<<<NB, 1024, 0, stream>>>(h0, gleak, vleak, cm, sigma, mu, w, erev,
                                            ow, ob, (const float2*)sens, out);
}

// Round 9
// 717.921 us; speedup vs baseline: 1.0911x; 1.0911x over previous
//
#include <hip/hip_runtime.h>

#define NB 16
#define NT 128
#define NC 64
#define NU 128
#define UNFOLDS 6
#define LTC_EPS 1e-8f
#define LOG2E 1.44269504088896340736f
#define LN2   0.69314718055994530942f

typedef float f32x2 __attribute__((ext_vector_type(2)));

__device__ __forceinline__ float fast_softplus(float x) {
    return LN2 * __builtin_amdgcn_logf(1.0f + __builtin_amdgcn_exp2f(x * LOG2E));
}

template<int CTRL>
__device__ __forceinline__ float qperm(float x) {
    return __int_as_float(__builtin_amdgcn_update_dpp(
        0, __float_as_int(x), CTRL, 0xF, 0xF, true));
}
// sum over the 8 lanes of a k-group; all stages DPP (VALU pipe, no LDS)
__device__ __forceinline__ float sum8(float x) {
    x += qperm<0xB1>(x);    // quad_perm xor-1
    x += qperm<0x4E>(x);    // quad_perm xor-2
    x += qperm<0x141>(x);   // row_half_mirror (verified r7)
    return x;
}

// ---------------- Kernel 1: sensory precompute (fully parallel) ----------------
__global__ __launch_bounds__(128)
void ltc_sens_kernel(const float* __restrict__ x,
                     const float* __restrict__ ssigma,
                     const float* __restrict__ smu,
                     const float* __restrict__ sw,
                     const float* __restrict__ serev,
                     const float* __restrict__ iw,
                     const float* __restrict__ ib,
                     float2* __restrict__ sens)
{
    __shared__ float xt[NC];
    const int blk = blockIdx.x;
    const int b = blk >> 7;
    const int t = blk & (NT - 1);
    const int j = threadIdx.x;
    if (j < NC) xt[j] = fmaf(x[(b * NT + t) * NC + j], iw[j], ib[j]);
    __syncthreads();

    float n0 = 0.f, n1 = 0.f, d0 = 0.f, d1 = 0.f;
#pragma unroll 8
    for (int c = 0; c < NC; ++c) {
        const int idx = c * NU + j;
        float sg = ssigma[idx];
        float m  = smu[idx];
        float wp = fast_softplus(sw[idx]);
        float er = serev[idx];
        float tt = (m - xt[c]) * (sg * LOG2E);
        float e  = __builtin_amdgcn_exp2f(tt);
        float r  = __builtin_amdgcn_rcpf(1.0f + e);
        float wr = wp * r;
        if (c & 1) { n1 = fmaf(wr, er, n1); d1 += wr; }
        else       { n0 = fmaf(wr, er, n0); d0 += wr; }
    }
    sens[(b * NT + t) * NU + j] = make_float2(n0 + n1, d0 + d1);
}

// ---------------- Kernel 2: sequential scan, 8 lanes per post-unit ----------------
__global__ __launch_bounds__(1024, 4)
void ltc_seq_kernel(const float* __restrict__ h0,
                    const float* __restrict__ gleak,
                    const float* __restrict__ vleak,
                    const float* __restrict__ cm,
                    const float* __restrict__ sigma,
                    const float* __restrict__ mu,
                    const float* __restrict__ w,
                    const float* __restrict__ erev,
                    const float* __restrict__ ow,
                    const float* __restrict__ ob,
                    const float2* __restrict__ sens,
                    float* __restrict__ out)
{
    __shared__ __align__(16) float v_lds[2][NU];

    const int tid = threadIdx.x;
    const int b   = blockIdx.x;
    const int j   = tid >> 3;   // post-unit (128)
    const int k   = tid & 7;    // pre-chunk (8 x 16 rows)

    // Transformed params, 2 pre-rows per slot. Slot q covers pre-rows
    // i0 = k*16 + 2g, i0+1 with g=(q+k)&7 (bank-conflict-free b64 v reads,
    // verified rounds 5-7).
    f32x2 rA2[8], rB2[8], rW2[8], aW2[8];
#pragma unroll
    for (int q = 0; q < 8; ++q) {
        const int g   = (q + k) & 7;
        const int i0  = (k << 4) + (g << 1);
        const int id0 = i0 * NU + j;
        const int id1 = id0 + NU;
        const float sg0 = sigma[id0], sg1 = sigma[id1];
        const float m0  = mu[id0],    m1  = mu[id1];
        const float wp0 = fast_softplus(w[id0]), wp1 = fast_softplus(w[id1]);
        const float er0 = erev[id0],  er1 = erev[id1];
        f32x2 a;  a.x = -sg0 * LOG2E;  a.y = -sg1 * LOG2E;
        f32x2 bb; bb.x = -a.x * m0;    bb.y = -a.y * m1;
        f32x2 ww; ww.x = wp0 * er0;    ww.y = wp1 * er1;
        f32x2 aw; aw.x = wp0;          aw.y = wp1;       // |w| (er = ±1)
        rA2[q] = a; rB2[q] = bb; rW2[q] = ww; aW2[q] = aw;
    }

    const float cmt    = 6.0f * fast_softplus(cm[j]);
    const float gl     = fast_softplus(gleak[j]);
    const float glv    = gl * vleak[j];
    const float cmt_gl = cmt + gl + LTC_EPS;
    const float owj    = ow[j];
    const float obj    = ob[j];
    float vj = h0[b * NU + j];
    if (k == 0) v_lds[0][j] = vj;
    __syncthreads();

    int p = 0;
    float2 s_cur = sens[b * NT * NU + j];

    for (int t = 0; t < NT; ++t) {
        // register pin (zero instructions; blocks reload/remat schemes)
#pragma unroll
        for (int q = 0; q < 8; ++q) {
            asm volatile("" : "+v"(rA2[q]), "+v"(rB2[q]), "+v"(rW2[q]), "+v"(aW2[q]));
        }

        // Per-step constants folded into accumulator init as lane-uniform
        // 1/8 injections (validated r8: absmax unchanged).
        const float nb = 0.125f * (s_cur.x + glv);
        const float db = 0.125f * (s_cur.y + cmt_gl);
        const int tn = (t + 1 < NT) ? (t + 1) : t;
        const float2 s_next = sens[(b * NT + tn) * NU + j];   // prefetch

#pragma unroll
        for (int u = 0; u < UNFOLDS; ++u) {
            f32x2 n2a = {nb, 0.f}, n2b = {0.f, 0.f};
            f32x2 d2a = {db, 0.f}, d2b = {0.f, 0.f};
#pragma unroll
            for (int h = 0; h < 4; ++h) {          // pairs (q0, q0+1)
                const int q0 = 2 * h;
                const int g0 = (q0 + k) & 7;
                const int g1 = (q0 + 1 + k) & 7;
                const f32x2 v0 = *(const f32x2*)&v_lds[p][(k << 4) + (g0 << 1)];
                const f32x2 v1 = *(const f32x2*)&v_lds[p][(k << 4) + (g1 << 1)];
                const f32x2 t0 = rA2[q0] * v0 + rB2[q0];
                const f32x2 t1 = rA2[q0 + 1] * v1 + rB2[q0 + 1];
                f32x2 e0, e1;
                e0.x = __builtin_amdgcn_exp2f(t0.x);
                e0.y = __builtin_amdgcn_exp2f(t0.y);
                e1.x = __builtin_amdgcn_exp2f(t1.x);
                e1.y = __builtin_amdgcn_exp2f(t1.y);
                const f32x2 one = {1.0f, 1.0f};
                const f32x2 u0 = e0 + one;
                const f32x2 u1 = e1 + one;
                // one rcp serves 4 sigmoids, swap-free recovery:
                // p2=(ac,bd); R=1/(abcd); rr=(R*bd, R*ac)=(1/ac,1/bd);
                // rr*u1=(1/a,1/b); rr*u0=(1/c,1/d).  |v|<1 => P<2^84 safe.
                const f32x2 p2 = u0 * u1;
                const float P  = p2.x * p2.y;
                const float R  = __builtin_amdgcn_rcpf(P);
                f32x2 rr;
                rr.x = R * p2.y;
                rr.y = R * p2.x;
                const f32x2 r0 = rr * u1;
                const f32x2 r1 = rr * u0;
                n2a = rW2[q0] * r0 + n2a;
                n2b = rW2[q0 + 1] * r1 + n2b;
                d2a = aW2[q0] * r0 + d2a;
                d2b = aW2[q0 + 1] * r1 + d2b;
            }
            const f32x2 n2 = n2a + n2b;
            const f32x2 d2 = d2a + d2b;
            const float wn = sum8(n2.x + n2.y);   // includes snum+glv
            const float wd = sum8(d2.x + d2.y);   // includes sden+cmt+gl+eps
            const float numf = fmaf(cmt, vj, wn);
            vj = numf * __builtin_amdgcn_rcpf(wd);   // redundant in 8 lanes
            if (k == 0) v_lds[p ^ 1][j] = vj;
            __syncthreads();                         // one barrier per unfold
            p ^= 1;
        }

        if (k == 0) out[(b * NT + t) * NU + j] = fmaf(vj, owj, obj);
        s_cur = s_next;
    }
    if (k == 0) out[NB * NT * NU + b * NU + j] = vj;    // h_final
}

extern "C" void kernel_launch(void* const* d_in, const int* in_sizes, int n_in,
                              void* d_out, int out_size, void* d_ws, size_t ws_size,
                              hipStream_t stream) {
    const float* x      = (const float*)d_in[0];
    const float* h0     = (const float*)d_in[1];
    const float* gleak  = (const float*)d_in[2];
    const float* vleak  = (const float*)d_in[3];
    const float* cm     = (const float*)d_in[4];
    const float* sigma  = (const float*)d_in[5];
    const float* mu     = (const float*)d_in[6];
    const float* w      = (const float*)d_in[7];
    const float* erev   = (const float*)d_in[8];
    const float* ssig   = (const float*)d_in[9];
    const float* smu    = (const float*)d_in[10];
    const float* sw     = (const float*)d_in[11];
    const float* serev  = (const float*)d_in[12];
    const float* iw     = (const float*)d_in[13];
    const float* ibv    = (const float*)d_in[14];
    const float* ow     = (const float*)d_in[15];
    const float* ob     = (const float*)d_in[16];
    float* out = (float*)d_out;

    float2* sens = (float2*)d_ws;   // 2 MB scratch
    ltc_sens_kernel<<<NB * NT, 128, 0, stream>>>(x, ssig, smu, sw, serev, iw, ibv, sens);
    ltc_seq_kernel<<<NB, 1024, 0, stream>>>(h0, gleak, vleak, cm, sigma, mu, w, erev,
                                            ow, ob, (const float2*)sens, out);
}